// Round 1
// baseline (336.807 us; speedup 1.0000x reference)
//
#include <hip/hip_runtime.h>
#include <hip/hip_bf16.h>
#include <stdint.h>

#define M_DIM 4096
#define N_DIM 10000
#define K_DIM 1024

typedef __attribute__((ext_vector_type(8))) short bf16x8;
typedef __attribute__((ext_vector_type(4))) float f32x4;

// async global->LDS, 16B per lane. LDS dest must be wave-uniform base + lane*16.
__device__ __forceinline__ void async_ld16(const void* g, void* l) {
    __builtin_amdgcn_global_load_lds(
        (const __attribute__((address_space(1))) unsigned int*)g,
        (__attribute__((address_space(3))) unsigned int*)l,
        16, 0, 0);
}

__device__ __forceinline__ unsigned short f2bf(float f) {
    unsigned u = __float_as_uint(f);
    unsigned r = (u + 0x7FFFu + ((u >> 16) & 1u)) >> 16;  // RNE
    return (unsigned short)r;
}

// One block per row: fp32 -> bf16 convert + exact fp32 squared-norm.
// K_DIM=1024, 256 threads -> one float4 per thread.
__global__ __launch_bounds__(256) void prep_rows(
    const float* __restrict__ in, unsigned short* __restrict__ outb,
    float* __restrict__ sq)
{
    const int row = blockIdx.x;
    const int t = threadIdx.x;
    const float4* ip = (const float4*)(in + (size_t)row * K_DIM);
    float4 v = ip[t];
    ushort4 pk;
    pk.x = f2bf(v.x); pk.y = f2bf(v.y); pk.z = f2bf(v.z); pk.w = f2bf(v.w);
    ((ushort4*)(outb + (size_t)row * K_DIM))[t] = pk;
    float s = v.x * v.x + v.y * v.y + v.z * v.z + v.w * v.w;
    #pragma unroll
    for (int off = 32; off > 0; off >>= 1) s += __shfl_down(s, off, 64);
    __shared__ float ws[4];
    if ((t & 63) == 0) ws[t >> 6] = s;
    __syncthreads();
    if (t == 0) sq[row] = ws[0] + ws[1] + ws[2] + ws[3];
}

// C[m][n] = sum_k A[m][k]*B[n][k]  (both K-major), epilogue adds norms.
// 128x128 tile, BK=32, 256 threads = 4 waves in 2x2, each wave 4x4 frags 16x16x32.
__global__ __launch_bounds__(256) void gemm_bt(
    const unsigned short* __restrict__ A,   // featbf [M][K]
    const unsigned short* __restrict__ B,   // centbf [N][K]
    const float* __restrict__ fsq, const float* __restrict__ csq,
    float* __restrict__ out)
{
    __shared__ unsigned short As[128 * 32];
    __shared__ unsigned short Bs[128 * 32];

    const int tid  = threadIdx.x;
    const int lane = tid & 63;
    const int wave = tid >> 6;
    const int wm = wave & 1, wn = wave >> 1;
    const int bm = blockIdx.y, bn = blockIdx.x;

    const int arow_base = bm * 128;
    const int brow_base = bn * 128;

    // staging: thread t covers rows t/4 and t/4+64, 8 bf16 at col (t%4)*8
    const int srow = tid >> 2;
    const int scol = (tid & 3) * 8;

    const unsigned short* gA0 = A + (size_t)(arow_base + srow) * K_DIM + scol;
    const unsigned short* gA1 = gA0 + (size_t)64 * K_DIM;
    int br0 = brow_base + srow;      if (br0 > N_DIM - 1) br0 = N_DIM - 1;
    int br1 = brow_base + 64 + srow; if (br1 > N_DIM - 1) br1 = N_DIM - 1;
    const unsigned short* gB0 = B + (size_t)br0 * K_DIM + scol;
    const unsigned short* gB1 = B + (size_t)br1 * K_DIM + scol;

    unsigned short* lA0 = As + tid * 8;         // base + lane*16B per wave
    unsigned short* lA1 = As + 2048 + tid * 8;
    unsigned short* lB0 = Bs + tid * 8;
    unsigned short* lB1 = Bs + 2048 + tid * 8;

    f32x4 acc[4][4];
    #pragma unroll
    for (int i = 0; i < 4; i++)
        #pragma unroll
        for (int j = 0; j < 4; j++) {
            f32x4 z = {0.f, 0.f, 0.f, 0.f};
            acc[i][j] = z;
        }

    const int mlane = lane & 15;
    const int quad  = lane >> 4;

    // A frag mi: As[(wm*64 + mi*16 + mlane)*32 + quad*8], 16B aligned
    const unsigned short* aptr = As + (wm * 64 + mlane) * 32 + quad * 8;
    const unsigned short* bptr = Bs + (wn * 64 + mlane) * 32 + quad * 8;

    for (int kt = 0; kt < K_DIM / 32; ++kt) {
        async_ld16(gA0, lA0);
        async_ld16(gA1, lA1);
        async_ld16(gB0, lB0);
        async_ld16(gB1, lB1);
        gA0 += 32; gA1 += 32; gB0 += 32; gB1 += 32;
        __syncthreads();   // compiler drains vmcnt before s_barrier

        bf16x8 af[4], bfv[4];
        #pragma unroll
        for (int i = 0; i < 4; i++) {
            af[i]  = *(const bf16x8*)(aptr + i * 16 * 32);
            bfv[i] = *(const bf16x8*)(bptr + i * 16 * 32);
        }
        #pragma unroll
        for (int i = 0; i < 4; i++)
            #pragma unroll
            for (int j = 0; j < 4; j++)
                acc[i][j] = __builtin_amdgcn_mfma_f32_16x16x32_bf16(
                    af[i], bfv[j], acc[i][j], 0, 0, 0);
        __syncthreads();   // before next staging overwrites LDS
    }

    // epilogue: C/D layout col=lane&15, row=quad*4+reg
    const int rbase = arow_base + wm * 64 + quad * 4;
    const int cbase = brow_base + wn * 64 + mlane;
    #pragma unroll
    for (int i = 0; i < 4; i++) {
        float frow[4];
        #pragma unroll
        for (int r = 0; r < 4; r++)
            frow[r] = -0.5f * fsq[rbase + i * 16 + r];
        #pragma unroll
        for (int j = 0; j < 4; j++) {
            int col = cbase + j * 16;
            if (col < N_DIM) {
                float cs = -0.5f * csq[col];
                #pragma unroll
                for (int r = 0; r < 4; r++) {
                    int row = rbase + i * 16 + r;
                    out[(size_t)row * N_DIM + col] = acc[i][j][r] + frow[r] + cs;
                }
            }
        }
    }
}

extern "C" void kernel_launch(void* const* d_in, const int* in_sizes, int n_in,
                              void* d_out, int out_size, void* d_ws, size_t ws_size,
                              hipStream_t stream) {
    const float* feat = (const float*)d_in[0];   // [4096,1024]
    const float* cent = (const float*)d_in[1];   // [10000,1024]
    float* out = (float*)d_out;                  // [4096,10000]

    char* ws = (char*)d_ws;
    unsigned short* featbf = (unsigned short*)ws;                         // 8,388,608 B
    unsigned short* centbf = (unsigned short*)(ws + 8388608);             // 20,480,000 B
    float* fsq = (float*)(ws + 8388608 + 20480000);                       // 16,384 B
    float* csq = (float*)(ws + 8388608 + 20480000 + 16384);               // 40,000 B

    prep_rows<<<M_DIM, 256, 0, stream>>>(feat, featbf, fsq);
    prep_rows<<<N_DIM, 256, 0, stream>>>(cent, centbf, csq);

    dim3 grid((N_DIM + 127) / 128, M_DIM / 128);   // 79 x 32
    gemm_bt<<<grid, 256, 0, stream>>>(featbf, centbf, fsq, csq, out);
}

// Round 2
// 308.857 us; speedup vs baseline: 1.0905x; 1.0905x over previous
//
#include <hip/hip_runtime.h>
#include <hip/hip_bf16.h>
#include <stdint.h>

#define M_DIM 4096
#define N_DIM 10000
#define K_DIM 1024
#define GM (M_DIM / 128)            // 32 row-tiles
#define GN ((N_DIM + 127) / 128)    // 79 col-tiles
#define SB 16                       // swizzle band width (bn)

typedef __attribute__((ext_vector_type(8))) short bf16x8;
typedef __attribute__((ext_vector_type(4))) float f32x4;

// async global->LDS, 16B per lane. LDS dest must be wave-uniform base + lane*16.
__device__ __forceinline__ void async_ld16(const void* g, void* l) {
    __builtin_amdgcn_global_load_lds(
        (const __attribute__((address_space(1))) unsigned int*)g,
        (__attribute__((address_space(3))) unsigned int*)l,
        16, 0, 0);
}

__device__ __forceinline__ unsigned short f2bf(float f) {
    unsigned u = __float_as_uint(f);
    unsigned r = (u + 0x7FFFu + ((u >> 16) & 1u)) >> 16;  // RNE
    return (unsigned short)r;
}

// One block per row (feat rows then center rows): fp32 -> bf16 + fp32 ||x||^2.
__global__ __launch_bounds__(256) void prep_rows(
    const float* __restrict__ feat, const float* __restrict__ cent,
    unsigned short* __restrict__ featbf, unsigned short* __restrict__ centbf,
    float* __restrict__ fsq, float* __restrict__ csq)
{
    const int row = blockIdx.x;
    const int t = threadIdx.x;
    const float* in;
    unsigned short* outb;
    float* sqp;
    if (row < M_DIM) {
        in = feat + (size_t)row * K_DIM;
        outb = featbf + (size_t)row * K_DIM;
        sqp = fsq + row;
    } else {
        const int r2 = row - M_DIM;
        in = cent + (size_t)r2 * K_DIM;
        outb = centbf + (size_t)r2 * K_DIM;
        sqp = csq + r2;
    }
    float4 v = ((const float4*)in)[t];
    ushort4 pk;
    pk.x = f2bf(v.x); pk.y = f2bf(v.y); pk.z = f2bf(v.z); pk.w = f2bf(v.w);
    ((ushort4*)outb)[t] = pk;
    float s = v.x * v.x + v.y * v.y + v.z * v.z + v.w * v.w;
    #pragma unroll
    for (int off = 32; off > 0; off >>= 1) s += __shfl_down(s, off, 64);
    __shared__ float ws[4];
    if ((t & 63) == 0) ws[t >> 6] = s;
    __syncthreads();
    if (t == 0) *sqp = ws[0] + ws[1] + ws[2] + ws[3];
}

// C[m][n] = sum_k A[m][k]*B[n][k]  (both K-major), epilogue adds norms.
// 128x128 tile, BK=32, 256 threads = 4 waves in 2x2, each wave 4x4 frags 16x16x32.
// 1D grid with supertile swizzle: bands of SB bn-tiles x all GM bm-tiles.
__global__ __launch_bounds__(256) void gemm_bt(
    const unsigned short* __restrict__ A,   // featbf [M][K]
    const unsigned short* __restrict__ B,   // centbf [N][K]
    const float* __restrict__ fsq, const float* __restrict__ csq,
    float* __restrict__ out)
{
    __shared__ unsigned short As[128 * 32];
    __shared__ unsigned short Bs[128 * 32];

    const int tid  = threadIdx.x;
    const int lane = tid & 63;
    const int wave = tid >> 6;
    const int wm = wave & 1, wn = wave >> 1;

    // supertile swizzle: band = SB bn-tiles wide, bm fastest within a band row
    const int lin  = blockIdx.x;
    const int band = lin / (SB * GM);
    const int r0   = lin - band * (SB * GM);
    const int bn0  = band * SB;
    int bw = GN - bn0; if (bw > SB) bw = SB;
    const int bm = r0 / bw;
    const int bn = bn0 + (r0 - bm * bw);

    const int arow_base = bm * 128;
    const int brow_base = bn * 128;

    // staging: thread t covers rows t/4 and t/4+64, 8 bf16 at col (t%4)*8
    const int srow = tid >> 2;
    const int scol = (tid & 3) * 8;

    const unsigned short* gA0 = A + (size_t)(arow_base + srow) * K_DIM + scol;
    const unsigned short* gA1 = gA0 + (size_t)64 * K_DIM;
    int br0 = brow_base + srow;      if (br0 > N_DIM - 1) br0 = N_DIM - 1;
    int br1 = brow_base + 64 + srow; if (br1 > N_DIM - 1) br1 = N_DIM - 1;
    const unsigned short* gB0 = B + (size_t)br0 * K_DIM + scol;
    const unsigned short* gB1 = B + (size_t)br1 * K_DIM + scol;

    unsigned short* lA0 = As + tid * 8;         // base + lane*16B per wave
    unsigned short* lA1 = As + 2048 + tid * 8;
    unsigned short* lB0 = Bs + tid * 8;
    unsigned short* lB1 = Bs + 2048 + tid * 8;

    f32x4 acc[4][4];
    #pragma unroll
    for (int i = 0; i < 4; i++)
        #pragma unroll
        for (int j = 0; j < 4; j++) {
            f32x4 z = {0.f, 0.f, 0.f, 0.f};
            acc[i][j] = z;
        }

    const int mlane = lane & 15;
    const int quad  = lane >> 4;

    const unsigned short* aptr = As + (wm * 64 + mlane) * 32 + quad * 8;
    const unsigned short* bptr = Bs + (wn * 64 + mlane) * 32 + quad * 8;

    for (int kt = 0; kt < K_DIM / 32; ++kt) {
        async_ld16(gA0, lA0);
        async_ld16(gA1, lA1);
        async_ld16(gB0, lB0);
        async_ld16(gB1, lB1);
        gA0 += 32; gA1 += 32; gB0 += 32; gB1 += 32;
        __syncthreads();   // compiler drains vmcnt before s_barrier

        bf16x8 af[4], bfv[4];
        #pragma unroll
        for (int i = 0; i < 4; i++) {
            af[i]  = *(const bf16x8*)(aptr + i * 16 * 32);
            bfv[i] = *(const bf16x8*)(bptr + i * 16 * 32);
        }
        #pragma unroll
        for (int i = 0; i < 4; i++)
            #pragma unroll
            for (int j = 0; j < 4; j++)
                acc[i][j] = __builtin_amdgcn_mfma_f32_16x16x32_bf16(
                    af[i], bfv[j], acc[i][j], 0, 0, 0);
        __syncthreads();   // before next staging overwrites LDS
    }

    // epilogue: C/D layout col=lane&15, row=quad*4+reg. Non-temporal stores so
    // the 162 MB output stream doesn't evict the 28 MB input slab from L2/L3.
    const int rbase = arow_base + wm * 64 + quad * 4;
    const int cbase = brow_base + wn * 64 + mlane;
    #pragma unroll
    for (int i = 0; i < 4; i++) {
        float frow[4];
        #pragma unroll
        for (int r = 0; r < 4; r++)
            frow[r] = -0.5f * fsq[rbase + i * 16 + r];
        #pragma unroll
        for (int j = 0; j < 4; j++) {
            int col = cbase + j * 16;
            if (col < N_DIM) {
                float cs = -0.5f * csq[col];
                #pragma unroll
                for (int r = 0; r < 4; r++) {
                    int row = rbase + i * 16 + r;
                    float v = acc[i][j][r] + frow[r] + cs;
                    __builtin_nontemporal_store(v, &out[(size_t)row * N_DIM + col]);
                }
            }
        }
    }
}

extern "C" void kernel_launch(void* const* d_in, const int* in_sizes, int n_in,
                              void* d_out, int out_size, void* d_ws, size_t ws_size,
                              hipStream_t stream) {
    const float* feat = (const float*)d_in[0];   // [4096,1024]
    const float* cent = (const float*)d_in[1];   // [10000,1024]
    float* out = (float*)d_out;                  // [4096,10000]

    char* ws = (char*)d_ws;
    unsigned short* featbf = (unsigned short*)ws;                         // 8,388,608 B
    unsigned short* centbf = (unsigned short*)(ws + 8388608);             // 20,480,000 B
    float* fsq = (float*)(ws + 8388608 + 20480000);                       // 16,384 B
    float* csq = (float*)(ws + 8388608 + 20480000 + 16384);               // 40,000 B

    prep_rows<<<M_DIM + N_DIM, 256, 0, stream>>>(feat, cent, featbf, centbf, fsq, csq);

    gemm_bt<<<GM * GN, 256, 0, stream>>>(featbf, centbf, fsq, csq, out);
}

// Round 4
// 296.746 us; speedup vs baseline: 1.1350x; 1.0408x over previous
//
#include <hip/hip_runtime.h>
#include <hip/hip_bf16.h>
#include <stdint.h>

#define M_DIM 4096
#define N_DIM 10000
#define K_DIM 1024
#define GM (M_DIM / 128)            // 32 row-tiles
#define GN ((N_DIM + 127) / 128)    // 79 col-tiles
#define SB 16                       // swizzle band width (bn); gives xcd = bn_local%8

typedef __attribute__((ext_vector_type(8))) short bf16x8;
typedef __attribute__((ext_vector_type(4))) float f32x4;

#define BAR()      asm volatile("s_barrier" ::: "memory")
#define WAITVM4()  asm volatile("s_waitcnt vmcnt(4)" ::: "memory")
#define WAITVM0()  asm volatile("s_waitcnt vmcnt(0)" ::: "memory")
#define WAITLGKM() asm volatile("s_waitcnt lgkmcnt(0)" ::: "memory")

// async global->LDS, 16B per lane. LDS dest must be wave-uniform base + lane*16.
__device__ __forceinline__ void async_ld16(const void* g, void* l) {
    __builtin_amdgcn_global_load_lds(
        (const __attribute__((address_space(1))) unsigned int*)g,
        (__attribute__((address_space(3))) unsigned int*)l,
        16, 0, 0);
}

__device__ __forceinline__ unsigned short f2bf(float f) {
    unsigned u = __float_as_uint(f);
    unsigned r = (u + 0x7FFFu + ((u >> 16) & 1u)) >> 16;  // RNE
    return (unsigned short)r;
}

// Wave-per-row: fp32 -> bf16 convert + exact fp32 ||x||^2. Grid-stride over
// the 14096 rows (feat then centers). 1024 floats/row = 64 lanes x 4 float4.
__global__ __launch_bounds__(256) void prep_rows(
    const float* __restrict__ feat, const float* __restrict__ cent,
    unsigned short* __restrict__ featbf, unsigned short* __restrict__ centbf,
    float* __restrict__ fsq, float* __restrict__ csq)
{
    const int wlane = threadIdx.x & 63;
    const int wid   = blockIdx.x * 4 + (threadIdx.x >> 6);
    const int nw    = gridDim.x * 4;
    for (int row = wid; row < M_DIM + N_DIM; row += nw) {
        const float* in;
        unsigned short* outb;
        float* sqp;
        if (row < M_DIM) {
            in = feat + (size_t)row * K_DIM;
            outb = featbf + (size_t)row * K_DIM;
            sqp = fsq + row;
        } else {
            const int r2 = row - M_DIM;
            in = cent + (size_t)r2 * K_DIM;
            outb = centbf + (size_t)r2 * K_DIM;
            sqp = csq + r2;
        }
        float s = 0.f;
        #pragma unroll
        for (int c = 0; c < 4; c++) {
            float4 v = ((const float4*)in)[wlane + c * 64];
            ushort4 pk;
            pk.x = f2bf(v.x); pk.y = f2bf(v.y); pk.z = f2bf(v.z); pk.w = f2bf(v.w);
            ((ushort4*)outb)[wlane + c * 64] = pk;
            s += v.x * v.x + v.y * v.y + v.z * v.z + v.w * v.w;
        }
        #pragma unroll
        for (int off = 32; off > 0; off >>= 1) s += __shfl_down(s, off, 64);
        if (wlane == 0) *sqp = s;
    }
}

// C[m][n] = sum_k A[m][k]*B[n][k] (both K-major), epilogue adds norms.
// 128x128 tile, BK=32, 4 waves 2x2, 4x4 frags of mfma 16x16x32 bf16.
// K-loop: LDS double-buffer, raw s_barrier + manual vmcnt(4) -- prefetch for
// tile k+1 stays in flight across the barrier (never waits vmcnt to 0 except
// the peeled last iteration). Epilogue: LDS transpose -> 256B-contiguous NT
// float4 stores.
__global__ __launch_bounds__(256) void gemm_bt(
    const unsigned short* __restrict__ A,   // featbf [M][K]
    const unsigned short* __restrict__ B,   // centbf [N][K]
    const float* __restrict__ fsq, const float* __restrict__ csq,
    float* __restrict__ out)
{
    // buf layout (shorts): buf*8192 + {A rows0-63:0, A rows64-127:2048,
    //                                  B rows0-63:4096, B rows64-127:6144}
    __shared__ unsigned short smem[16384];  // 32 KB: two 16 KB buffers

    const int tid  = threadIdx.x;
    const int lane = tid & 63;
    const int wave = tid >> 6;
    const int wm = wave & 1, wn = wave >> 1;

    // supertile swizzle: band = SB bn-tiles x all GM bm-tiles; within a band
    // r0 = bm*bw + bn_local so xcd(=lin%8) = bn_local%8 -> 2 B-tiles per XCD.
    const int lin  = blockIdx.x;
    const int band = lin / (SB * GM);
    const int r0   = lin - band * (SB * GM);
    const int bn0  = band * SB;
    int bw = GN - bn0; if (bw > SB) bw = SB;
    const int bm = r0 / bw;
    const int bn = bn0 + (r0 - bm * bw);

    const int arow_base = bm * 128;
    const int brow_base = bn * 128;

    // staging: thread t covers rows t/4 and t/4+64, 8 bf16 at col (t%4)*8
    const int srow = tid >> 2;
    const int scol = (tid & 3) * 8;

    const unsigned short* gA0 = A + (size_t)(arow_base + srow) * K_DIM + scol;
    const unsigned short* gA1 = gA0 + (size_t)64 * K_DIM;
    int br0 = brow_base + srow;      if (br0 > N_DIM - 1) br0 = N_DIM - 1;
    int br1 = brow_base + 64 + srow; if (br1 > N_DIM - 1) br1 = N_DIM - 1;
    const unsigned short* gB0 = B + (size_t)br0 * K_DIM + scol;
    const unsigned short* gB1 = B + (size_t)br1 * K_DIM + scol;

    f32x4 acc[4][4];
    #pragma unroll
    for (int i = 0; i < 4; i++)
        #pragma unroll
        for (int j = 0; j < 4; j++) {
            f32x4 z = {0.f, 0.f, 0.f, 0.f};
            acc[i][j] = z;
        }

    const int mlane = lane & 15;
    const int quad  = lane >> 4;
    const int aoff = (wm * 64 + mlane) * 32 + quad * 8;       // within A region
    const int boff = 4096 + (wn * 64 + mlane) * 32 + quad * 8;

    // prologue: stage tile 0 into buf0
    async_ld16(gA0, smem + tid * 8);
    async_ld16(gA1, smem + 2048 + tid * 8);
    async_ld16(gB0, smem + 4096 + tid * 8);
    async_ld16(gB1, smem + 6144 + tid * 8);
    gA0 += 32; gA1 += 32; gB0 += 32; gB1 += 32;

    #define COMPUTE(bufbase)                                                  \
        do {                                                                  \
            const unsigned short* ap = smem + (bufbase) + aoff;               \
            const unsigned short* bp = smem + (bufbase) + boff;               \
            bf16x8 af[4], bfv[4];                                             \
            _Pragma("unroll")                                                 \
            for (int i = 0; i < 4; i++) {                                     \
                af[i]  = *(const bf16x8*)(ap + i * 16 * 32);                  \
                bfv[i] = *(const bf16x8*)(bp + i * 16 * 32);                  \
            }                                                                 \
            _Pragma("unroll")                                                 \
            for (int i = 0; i < 4; i++)                                       \
                _Pragma("unroll")                                             \
                for (int j = 0; j < 4; j++)                                   \
                    acc[i][j] = __builtin_amdgcn_mfma_f32_16x16x32_bf16(      \
                        af[i], bfv[j], acc[i][j], 0, 0, 0);                   \
        } while (0)

    for (int kt = 0; kt < K_DIM / 32 - 1; ++kt) {
        const int buf  = kt & 1;
        const int nbase = (buf ^ 1) * 8192;
        // prefetch tile kt+1 into the other buffer (prev-iter end barrier
        // guarantees everyone is done reading it)
        async_ld16(gA0, smem + nbase + tid * 8);
        async_ld16(gA1, smem + nbase + 2048 + tid * 8);
        async_ld16(gB0, smem + nbase + 4096 + tid * 8);
        async_ld16(gB1, smem + nbase + 6144 + tid * 8);
        gA0 += 32; gA1 += 32; gB0 += 32; gB1 += 32;
        WAITVM4();   // oldest 4 (tile kt, this buffer) done; prefetch in flight
        BAR();
        COMPUTE(buf * 8192);
        BAR();       // all ds_reads of this buffer done before kt+1 overwrites
    }
    WAITVM0();       // peeled last tile (kt=31, buf1)
    BAR();
    COMPUTE(8192);
    BAR();           // LDS about to be reused by epilogue

    // epilogue: fold norms, transpose 16x64 chunks through LDS, NT f32x4
    // stores (256B contiguous per row segment vs 64B in the direct layout).
    float* W = (float*)smem + wave * 1088;   // 16 rows x stride 68
    const int rbase0 = arow_base + wm * 64;
    const int cbase  = brow_base + wn * 64 + mlane;
    const int rb_col4 = mlane * 4;           // readback: lane -> 4 cols
    const int rb_rows = quad;                // readback: lane -> row-in-group
    const int gcol4 = brow_base + wn * 64 + rb_col4;
    const bool colok = gcol4 < N_DIM;        // 4-aligned, N%4==0 -> +3 safe

    #pragma unroll
    for (int i = 0; i < 4; i++) {
        float frow[4];
        #pragma unroll
        for (int r = 0; r < 4; r++)
            frow[r] = -0.5f * fsq[rbase0 + i * 16 + quad * 4 + r];
        #pragma unroll
        for (int j = 0; j < 4; j++) {
            int col = cbase + j * 16;
            float cs = -0.5f * csq[col < N_DIM ? col : (N_DIM - 1)];
            #pragma unroll
            for (int r = 0; r < 4; r++)
                W[(quad * 4 + r) * 68 + j * 16 + mlane] = acc[i][j][r] + frow[r] + cs;
        }
        WAITLGKM();  // writes visible to own-wave reads
        #pragma unroll
        for (int s = 0; s < 4; s++) {
            int rl = s * 4 + rb_rows;
            f32x4 v = *(const f32x4*)&W[rl * 68 + rb_col4];
            if (colok) {
                int grow = rbase0 + i * 16 + rl;
                __builtin_nontemporal_store(v, (f32x4*)&out[(size_t)grow * N_DIM + gcol4]);
            }
        }
        WAITLGKM();  // reads done before next i overwrites W
    }
    #undef COMPUTE
}

extern "C" void kernel_launch(void* const* d_in, const int* in_sizes, int n_in,
                              void* d_out, int out_size, void* d_ws, size_t ws_size,
                              hipStream_t stream) {
    const float* feat = (const float*)d_in[0];   // [4096,1024]
    const float* cent = (const float*)d_in[1];   // [10000,1024]
    float* out = (float*)d_out;                  // [4096,10000]

    char* ws = (char*)d_ws;
    unsigned short* featbf = (unsigned short*)ws;                         // 8,388,608 B
    unsigned short* centbf = (unsigned short*)(ws + 8388608);             // 20,480,000 B
    float* fsq = (float*)(ws + 8388608 + 20480000);                       // 16,384 B
    float* csq = (float*)(ws + 8388608 + 20480000 + 16384);               // 40,000 B

    prep_rows<<<1024, 256, 0, stream>>>(feat, cent, featbf, centbf, fsq, csq);

    gemm_bt<<<GM * GN, 256, 0, stream>>>(featbf, centbf, fsq, csq, out);
}